// Round 9
// baseline (241.445 us; speedup 1.0000x reference)
//
#include <hip/hip_runtime.h>
#include <math.h>

#define P_ 32
#define G_ 256
#define NV 6890
#define M_ (2 * NV)          // 13780 joint points per sample
#define QUADS (M_ / 4)       // 3445 vertex-quads (exact)
#define NPAIR (P_ * G_)      // 8192
#define NB_WS 512            // wave-split crosscov blocks (2-way quad split)
#define CHUNK_Q 128          // quads staged to LDS per chunk
#define NCHUNKS ((QUADS + CHUNK_Q - 1) / CHUNK_Q)   // 27 (tail = 117)
#define HALF_CH 14           // chunks in quad-half 0 (half 1 gets 13)

typedef float v2f __attribute__((ext_vector_type(2)));
__device__ inline v2f v2(float a, float b) { v2f r; r.x = a; r.y = b; return r; }
__device__ inline v2f vsplat(float a) { v2f r; r.x = a; r.y = a; return r; }
__device__ inline v2f vfma(v2f a, v2f b, v2f c) { return __builtin_elementwise_fma(a, b, c); }

// ---------------- workspace layout (~0.6 MB) ----------------
struct WS {
    float mu_p[P_][3];
    float var_p[P_];
    float mu_g[G_][3];
    float Kmat[2][NPAIR][9];  // partial cross-cov per quad-half; pair = g*32+p
    float pair_err[NPAIR];    // mean v2v error per pair
};

// ---------------- block reduction (valid on thread 0; supports 512 thr) ----
__device__ inline double block_reduce(double v, double* smem) {
#pragma unroll
    for (int off = 32; off > 0; off >>= 1) v += __shfl_down(v, off, 64);
    int wid  = threadIdx.x >> 6;
    int lane = threadIdx.x & 63;
    __syncthreads();
    if (lane == 0) smem[wid] = v;
    __syncthreads();
    double r = 0.0;
    if (threadIdx.x == 0) {
        int nw = blockDim.x >> 6;
        for (int w = 0; w < nw; ++w) r += smem[w];
    }
    return r;
}

// ---------------- kernel 1: wave-split crosscov (8p x 4g x qhalf) --------
// R7 lesson: reg-prefetch across __syncthreads is VOID (compiler drains
// vmcnt(0) before s_barrier) and its +12 VGPR (64->76) capped waves at
// 16/CU. Direct staging: VGPR<=64 -> 32-wave/CU ceiling -> 4 co-resident
// blocks/CU whose stage/compute phases interleave.
// Wave w owns p = pbase+w (4 pairs, 36 acc floats). g-streams staged to
// LDS deinterleaved xyz planes per 128-quad chunk (24 KB).
// Blocks 0..511: bx = qhalf*256 + ptile*64 + gtile; XCD = gtile%8.
// Blocks 512..799: per-sample stats (0..31 pred mu/var, 32..287 gt mu).
__global__ __launch_bounds__(512) void crosscov_ws(const float* __restrict__ pred,
                                                   const float* __restrict__ gt,
                                                   WS* __restrict__ ws) {
    int bx = blockIdx.x;
    int t = threadIdx.x;

    if (bx >= NB_WS) {
        // ---- stats path (512-thread grid-stride) ----
        int b = bx - NB_WS;
        bool isP = (b < P_);
        const float* base = isP ? pred + (size_t)b * (M_ * 3)
                                : gt + (size_t)(b - P_) * (M_ * 3);
        double sx = 0, sy = 0, sz = 0, sq = 0;
        for (int q = t; q < QUADS; q += 512) {
            const float4* p4 = (const float4*)(base + 12 * (size_t)q);
            float4 a = p4[0], c = p4[1], d = p4[2];
            sx += (double)a.x + (double)a.w + (double)c.z + (double)d.y;
            sy += (double)a.y + (double)c.x + (double)c.w + (double)d.z;
            sz += (double)a.z + (double)c.y + (double)d.x + (double)d.w;
            if (isP) {
                sq += (double)a.x * a.x + (double)a.y * a.y + (double)a.z * a.z +
                      (double)a.w * a.w + (double)c.x * c.x + (double)c.y * c.y +
                      (double)c.z * c.z + (double)c.w * c.w + (double)d.x * d.x +
                      (double)d.y * d.y + (double)d.z * d.z + (double)d.w * d.w;
            }
        }
        __shared__ double smem[8];
        double rx = block_reduce(sx, smem);
        double ry = block_reduce(sy, smem);
        double rz = block_reduce(sz, smem);
        double rq = block_reduce(sq, smem);
        if (t == 0) {
            double mx = rx / M_, my = ry / M_, mz = rz / M_;
            if (isP) {
                ws->mu_p[b][0] = (float)mx;
                ws->mu_p[b][1] = (float)my;
                ws->mu_p[b][2] = (float)mz;
                ws->var_p[b] = (float)(rq - (mx * mx + my * my + mz * mz) * (double)M_);
            } else {
                ws->mu_g[b - P_][0] = (float)mx;
                ws->mu_g[b - P_][1] = (float)my;
                ws->mu_g[b - P_][2] = (float)mz;
            }
        }
        return;
    }

    // ---- wave-split crosscov path ----
    int qhalf = bx >> 8;           // 0 or 1
    int rem = bx & 255;
    int gbase = (rem & 63) * 4;
    int pbase = (rem >> 6) * 8;    // 4 ptiles of 8
    int c0 = qhalf * HALF_CH;
    int c1 = qhalf ? NCHUNKS : HALF_CH;
    int wave = t >> 6;
    int lane = t & 63;
    int p = pbase + wave;          // this wave's pred sample

    const float* pb = pred + (size_t)p * (M_ * 3);
    // staging assignment: thread t stages stream ss, f4 slots si, si+128, si+256
    int ss = t >> 7;               // 0..3
    int si = t & 127;
    const float4* gsrc = (const float4*)(gt + (size_t)(gbase + ss) * (M_ * 3));

    // LDS: xyz planes per g-stream, CHUNK_Q*4 points each => 24 KB
    __shared__ __align__(16) float glds[3][4][CHUNK_Q * 4];

    v2f a01[4], a34[4], a67[4], a25[4];
    float a8[4];
#pragma unroll
    for (int i = 0; i < 4; ++i) {
        a01[i] = vsplat(0.f); a34[i] = vsplat(0.f);
        a25[i] = vsplat(0.f); a67[i] = vsplat(0.f);
        a8[i] = 0.f;
    }

    for (int c = c0; c < c1; ++c) {
        int qb = c * CHUNK_Q;
        int nq = QUADS - qb; if (nq > CHUNK_Q) nq = CHUNK_Q;
        __syncthreads();   // previous chunk's LDS reads done
        // stage + deinterleave: 3 f4 per thread, scalar writes to planes
#pragma unroll
        for (int r = 0; r < 3; ++r) {
            int fi = si + r * 128;                 // f4 index in stream-chunk
            if (fi < 3 * nq) {
                float4 v = gsrc[(size_t)qb * 3 + fi];
                float vv[4] = { v.x, v.y, v.z, v.w };
#pragma unroll
                for (int j = 0; j < 4; ++j) {
                    int f = 4 * fi + j;            // float index in chunk
                    glds[f % 3][ss][f / 3] = vv[j];
                }
            }
        }
        __syncthreads();   // chunk staged
#pragma unroll
        for (int sub = 0; sub < 2; ++sub) {
            int qq = lane + sub * 64;
            if (qq < nq) {
                const float4* p4 = (const float4*)(pb + 12 * (size_t)(qb + qq));
                float4 Pa = p4[0], Pc = p4[1], Pd = p4[2];
                float x[4] = { Pa.x, Pa.w, Pc.z, Pd.y };
                float y[4] = { Pa.y, Pc.x, Pc.w, Pd.z };
                float z[4] = { Pa.z, Pc.y, Pd.x, Pd.w };
#pragma unroll
                for (int gg = 0; gg < 4; ++gg) {
                    float4 GX = *(const float4*)&glds[0][gg][4 * qq];
                    float4 GY = *(const float4*)&glds[1][gg][4 * qq];
                    float4 GZ = *(const float4*)&glds[2][gg][4 * qq];
                    float gxv[4] = { GX.x, GX.y, GX.z, GX.w };
                    float gyv[4] = { GY.x, GY.y, GY.z, GY.w };
                    float gzv[4] = { GZ.x, GZ.y, GZ.z, GZ.w };
#pragma unroll
                    for (int k = 0; k < 4; ++k) {
                        v2f gxy = v2(gxv[k], gyv[k]);
                        a01[gg] = vfma(vsplat(x[k]), gxy, a01[gg]);
                        a34[gg] = vfma(vsplat(y[k]), gxy, a34[gg]);
                        a67[gg] = vfma(vsplat(z[k]), gxy, a67[gg]);
                        a25[gg] = vfma(v2(x[k], y[k]), vsplat(gzv[k]), a25[gg]);
                        a8[gg]  = fmaf(z[k], gzv[k], a8[gg]);
                    }
                }
            }
        }
    }

    // per-wave butterfly; (qhalf, pair) owned by exactly this wave
    float K[4][9];
#pragma unroll
    for (int i = 0; i < 4; ++i) {
        K[i][0] = a01[i].x; K[i][1] = a01[i].y; K[i][2] = a25[i].x;
        K[i][3] = a34[i].x; K[i][4] = a34[i].y; K[i][5] = a25[i].y;
        K[i][6] = a67[i].x; K[i][7] = a67[i].y; K[i][8] = a8[i];
    }
#pragma unroll
    for (int i = 0; i < 4; ++i)
#pragma unroll
        for (int j = 0; j < 9; ++j) {
            float v = K[i][j];
            v += __shfl_xor(v, 1);  v += __shfl_xor(v, 2);
            v += __shfl_xor(v, 4);  v += __shfl_xor(v, 8);
            v += __shfl_xor(v, 16); v += __shfl_xor(v, 32);
            K[i][j] = v;
        }
    if (lane == 0) {
#pragma unroll
        for (int gg = 0; gg < 4; ++gg)
#pragma unroll
            for (int j = 0; j < 9; ++j)
                ws->Kmat[qhalf][(gbase + gg) * P_ + p][j] = K[gg][j];
    }
}

// ---------------- device: per-pair SVD -> A[9], t[3] (fp64, unchanged math)
__device__ void svd_pair(const WS* __restrict__ ws, int p, int g, float* __restrict__ A_out) {
    int pair = g * P_ + p;
    double mp[3] = { ws->mu_p[p][0], ws->mu_p[p][1], ws->mu_p[p][2] };
    double mg[3] = { ws->mu_g[g][0], ws->mu_g[g][1], ws->mu_g[g][2] };
    double varp = (double)ws->var_p[p];

    double K[3][3];
#pragma unroll
    for (int a = 0; a < 3; ++a)
#pragma unroll
        for (int b = 0; b < 3; ++b)
            K[a][b] = (double)ws->Kmat[0][pair][3 * a + b] +
                      (double)ws->Kmat[1][pair][3 * a + b] -
                      (double)M_ * mp[a] * mg[b];

    double S[3][3];
#pragma unroll
    for (int a = 0; a < 3; ++a)
#pragma unroll
        for (int b = 0; b < 3; ++b) {
            double acc = 0.0;
#pragma unroll
            for (int c = 0; c < 3; ++c) acc += K[c][a] * K[c][b];
            S[a][b] = acc;
        }

    double V[3][3] = { {1, 0, 0}, {0, 1, 0}, {0, 0, 1} };
    double tr = S[0][0] + S[1][1] + S[2][2];
    double tol = 1e-30 * tr * tr + 1e-300;
    const int PP[3] = {0, 0, 1};
    const int QQ[3] = {1, 2, 2};
    for (int sweep = 0; sweep < 30; ++sweep) {
        double off = S[0][1] * S[0][1] + S[0][2] * S[0][2] + S[1][2] * S[1][2];
        if (off <= tol) break;
        for (int r3 = 0; r3 < 3; ++r3) {
            int pq = PP[r3], qq = QQ[r3];
            double apq = S[pq][qq];
            if (apq == 0.0) continue;
            double theta = (S[qq][qq] - S[pq][pq]) / (2.0 * apq);
            double tt = copysign(1.0, theta) / (fabs(theta) + sqrt(theta * theta + 1.0));
            double c = 1.0 / sqrt(tt * tt + 1.0);
            double sj = tt * c;
            for (int r = 0; r < 3; ++r) {
                double srp = S[r][pq], srq = S[r][qq];
                S[r][pq] = c * srp - sj * srq;
                S[r][qq] = sj * srp + c * srq;
            }
            for (int cc = 0; cc < 3; ++cc) {
                double spr = S[pq][cc], sqr = S[qq][cc];
                S[pq][cc] = c * spr - sj * sqr;
                S[qq][cc] = sj * spr + c * sqr;
            }
            for (int r = 0; r < 3; ++r) {
                double vrp = V[r][pq], vrq = V[r][qq];
                V[r][pq] = c * vrp - sj * vrq;
                V[r][qq] = sj * vrp + c * vrq;
            }
        }
    }

    double lam[3] = { S[0][0], S[1][1], S[2][2] };
    int idx[3] = { 0, 1, 2 };
    if (lam[idx[0]] < lam[idx[1]]) { int tt = idx[0]; idx[0] = idx[1]; idx[1] = tt; }
    if (lam[idx[0]] < lam[idx[2]]) { int tt = idx[0]; idx[0] = idx[2]; idx[2] = tt; }
    if (lam[idx[1]] < lam[idx[2]]) { int tt = idx[1]; idx[1] = idx[2]; idx[2] = tt; }
    double Vs[3][3];
    double sv[3];
#pragma unroll
    for (int i = 0; i < 3; ++i) {
        double l = lam[idx[i]];
        sv[i] = sqrt(l > 0.0 ? l : 0.0);
        for (int r = 0; r < 3; ++r) Vs[r][i] = V[r][idx[i]];
    }

    double U[3][3];
#pragma unroll
    for (int i = 0; i < 3; ++i) {
        double kx = K[0][0] * Vs[0][i] + K[0][1] * Vs[1][i] + K[0][2] * Vs[2][i];
        double ky = K[1][0] * Vs[0][i] + K[1][1] * Vs[1][i] + K[1][2] * Vs[2][i];
        double kz = K[2][0] * Vs[0][i] + K[2][1] * Vs[1][i] + K[2][2] * Vs[2][i];
        double inv = (sv[i] > 1e-12 * sv[0] && sv[i] > 0.0) ? 1.0 / sv[i] : 0.0;
        U[0][i] = kx * inv; U[1][i] = ky * inv; U[2][i] = kz * inv;
    }
    if (sv[2] <= 1e-12 * sv[0] || sv[0] == 0.0) {
        U[0][2] = U[1][0] * U[2][1] - U[2][0] * U[1][1];
        U[1][2] = U[2][0] * U[0][1] - U[0][0] * U[2][1];
        U[2][2] = U[0][0] * U[1][1] - U[1][0] * U[0][1];
    }

    double detK = K[0][0] * (K[1][1] * K[2][2] - K[1][2] * K[2][1])
                - K[0][1] * (K[1][0] * K[2][2] - K[1][2] * K[2][0])
                + K[0][2] * (K[1][0] * K[2][1] - K[1][1] * K[2][0]);
    double d = (detK >= 0.0) ? 1.0 : -1.0;
    double scale = (sv[0] + sv[1] + d * sv[2]) / varp;

#pragma unroll
    for (int a = 0; a < 3; ++a)
#pragma unroll
        for (int b = 0; b < 3; ++b) {
            double r = Vs[a][0] * U[b][0] + Vs[a][1] * U[b][1] + d * Vs[a][2] * U[b][2];
            A_out[3 * a + b] = (float)(scale * r);
        }
#pragma unroll
    for (int a = 0; a < 3; ++a)
        A_out[9 + a] = (float)(mg[a] - ((double)A_out[3 * a + 0] * mp[0] +
                                        (double)A_out[3 * a + 1] * mp[1] +
                                        (double)A_out[3 * a + 2] * mp[2]));
}

// ---------------- kernel 2: fused SVD prologue + v2v error (2p x 4g) ------
// 1024 blocks. Threads 0..7 each compute one pair's SVD->A,t into LDS (each
// pair's At is consumed by exactly this block -> zero redundancy, and the
// standalone 128-wave svd dispatch disappears). Error loop = proven R0 shape.
__global__ __launch_bounds__(256) void pair_error_f(const float* __restrict__ pred,
                                                    const float* __restrict__ gt,
                                                    WS* __restrict__ ws) {
    int bx = blockIdx.x;
    int gbase = (bx & 63) * 4;
    int pbase = (bx >> 6) * 2;
    int t = threadIdx.x;

    __shared__ float Atile[8][12];
    if (t < 8) {
        int gg = t >> 1, pp = t & 1;
        float A[12];
        svd_pair(ws, pbase + pp, gbase + gg, A);
#pragma unroll
        for (int j = 0; j < 12; ++j) Atile[t][j] = A[j];
    }
    __syncthreads();

    v2f a03[8], a14[8], a25v[8], t01[8];
    float a6[8], a7[8], a8v[8], t2[8];
#pragma unroll
    for (int i = 0; i < 8; ++i) {
        const float* At = Atile[i];
        a03[i] = v2(At[0], At[3]);
        a14[i] = v2(At[1], At[4]);
        a25v[i] = v2(At[2], At[5]);
        t01[i] = v2(At[9], At[10]);
        a6[i] = At[6]; a7[i] = At[7]; a8v[i] = At[8]; t2[i] = At[11];
    }

    const float* pb0 = pred + (size_t)pbase * (M_ * 3);
    const float* pb1 = pred + (size_t)(pbase + 1) * (M_ * 3);
    const float* gb[4];
#pragma unroll
    for (int j = 0; j < 4; ++j) gb[j] = gt + (size_t)(gbase + j) * (M_ * 3);

    float acc[8];
#pragma unroll
    for (int i = 0; i < 8; ++i) acc[i] = 0.f;

    for (int q = t; q < QUADS; q += 256) {
        float4 P[2][3];
        {
            const float4* p4 = (const float4*)(pb0 + 12 * (size_t)q);
            P[0][0] = p4[0]; P[0][1] = p4[1]; P[0][2] = p4[2];
            p4 = (const float4*)(pb1 + 12 * (size_t)q);
            P[1][0] = p4[0]; P[1][1] = p4[1]; P[1][2] = p4[2];
        }
#pragma unroll
        for (int gg = 0; gg < 4; ++gg) {
            const float4* g4 = (const float4*)(gb[gg] + 12 * (size_t)q);
            float4 Ga = g4[0], Gc = g4[1], Gd = g4[2];
            v2f gxy[4] = { v2(Ga.x, Ga.y), v2(Ga.w, Gc.x), v2(Gc.z, Gc.w), v2(Gd.y, Gd.z) };
            float gz[4] = { Ga.z, Gc.y, Gd.x, Gd.w };
#pragma unroll
            for (int pp = 0; pp < 2; ++pp) {
                int i = gg * 2 + pp;
                float4 Pa = P[pp][0], Pc = P[pp][1], Pd = P[pp][2];
                float x[4] = { Pa.x, Pa.w, Pc.z, Pd.y };
                float y[4] = { Pa.y, Pc.x, Pc.w, Pd.z };
                float z[4] = { Pa.z, Pc.y, Pd.x, Pd.w };
                float s = 0.f;
#pragma unroll
                for (int k = 0; k < 4; ++k) {
                    v2f dd = vfma(a03[i], vsplat(x[k]),
                             vfma(a14[i], vsplat(y[k]),
                             vfma(a25v[i], vsplat(z[k]), t01[i])));
                    dd = dd - gxy[k];
                    float dz = fmaf(a6[i], x[k], fmaf(a7[i], y[k], fmaf(a8v[i], z[k], t2[i]))) - gz[k];
                    v2f m = dd * dd;
                    s += __builtin_amdgcn_sqrtf(fmaf(dz, dz, m.x + m.y));
                }
                acc[i] += s;
            }
        }
    }

#pragma unroll
    for (int i = 0; i < 8; ++i) {
        float v = acc[i];
        v += __shfl_xor(v, 1);  v += __shfl_xor(v, 2);
        v += __shfl_xor(v, 4);  v += __shfl_xor(v, 8);
        v += __shfl_xor(v, 16); v += __shfl_xor(v, 32);
        acc[i] = v;
    }
    __shared__ float part[4][8];
    int lane = t & 63, wave = t >> 6;
    if (lane == 0) {
#pragma unroll
        for (int i = 0; i < 8; ++i) part[wave][i] = acc[i];
    }
    __syncthreads();
    if (t < 8) {
        float s = part[0][t] + part[1][t] + part[2][t] + part[3][t];
        int gg = t >> 1, pp = t & 1;
        ws->pair_err[(gbase + gg) * P_ + (pbase + pp)] = s / (float)M_;
    }
}

// ---------------- kernel 3: argmin over gallery + write outputs ----------------
__global__ void argmin_out(const WS* __restrict__ ws, float* __restrict__ out) {
    __shared__ float be[8][32];
    __shared__ int   bg[8][32];
    int t = threadIdx.x;
    int p = t & 31, slice = t >> 5;
    float best = 3.4e38f;
    int bi = G_;
    for (int g = slice; g < G_; g += 8) {
        float e = ws->pair_err[g * P_ + p];
        if (e < best) { best = e; bi = g; }
    }
    be[slice][p] = best;
    bg[slice][p] = bi;
    __syncthreads();
    if (t < P_) {
        float b0 = be[0][t];
        int   i0 = bg[0][t];
        for (int s = 1; s < 8; ++s) {
            float e = be[s][t];
            int   i = bg[s][t];
            if (e < b0 || (e == b0 && i < i0)) { b0 = e; i0 = i; }
        }
        out[t] = (float)i0;
        out[P_ + t] = b0;
    }
}

extern "C" void kernel_launch(void* const* d_in, const int* in_sizes, int n_in,
                              void* d_out, int out_size, void* d_ws, size_t ws_size,
                              hipStream_t stream) {
    const float* pred = (const float*)d_in[0];   // (32, 2, 6890, 3)
    const float* gt   = (const float*)d_in[1];   // (256, 2, 6890, 3)
    float* out = (float*)d_out;                  // 64 floats: mapping(32) | min_error(32)
    WS* ws = (WS*)d_ws;                          // ~0.6 MB used

    crosscov_ws<<<dim3(NB_WS + P_ + G_), dim3(512), 0, stream>>>(pred, gt, ws);
    pair_error_f<<<dim3(16 * 64), dim3(256), 0, stream>>>(pred, gt, ws);
    argmin_out<<<dim3(1), dim3(256), 0, stream>>>(ws, out);
}